// Round 14
// baseline (61.198 us; speedup 1.0000x reference)
//
#include <hip/hip_runtime.h>

#define GAMMA 0.1f

constexpr int MTOT = 65536;
constexpr int NTOT = 1024;
constexpr int KDIM = 64;
constexpr int RPB  = 256;        // rows per block
constexpr int CPB  = 512;        // centers (cols) per block -> 2 blocks/CU
constexpr int SUB  = 32;         // rows per sub-tile
constexpr int NSUB = RPB / SUB;  // 8 iterations
// grid = 512: block b -> col-half nh=b>>8, rows mb=b&255. Blocks i and i+256
// (likely co-resident, same XCD) cover the SAME rows, different col halves:
// shared x reads, interleaved stores in the same 4KB rows, offset phases.

using f16x8 = __attribute__((ext_vector_type(8))) _Float16;  // MFMA A/B frag
using f16x4 = __attribute__((ext_vector_type(4))) _Float16;  // 8-B LDS store
using f32x4 = __attribute__((ext_vector_type(4))) float;     // MFMA C/D

__global__ __launch_bounds__(512, 2)
void rbf_fused_kernel(const float* __restrict__ x,
                      const float* __restrict__ centers,
                      float* __restrict__ out) {
  __shared__ _Float16 sCen[CPB * KDIM];       // 64 KB, staged once, read-only
  __shared__ _Float16 sX[2][SUB * KDIM];      // 8 KB dbuf (XOR-swizzled)
  __shared__ float    sCsq[CPB];              // 2 KB
  __shared__ float    sXsq[2][SUB];           // 256 B
  // total ~74.3 KB -> 2 blocks/CU (16 waves/CU)

  const int tid = threadIdx.x;
  const int nh = blockIdx.x >> 8;             // 0..1 col half
  const int mb = blockIdx.x & 255;            // row group

  const float4* xsrc = reinterpret_cast<const float4*>(x + (size_t)mb * RPB * KDIM);

  // x sub-tile convert: thread owns float4 #tid -> row tid>>4 (0..31), slot-half
  auto convert_x = [&](float4 v4, int buf) {
    const int row = tid >> 4;
    const int f15 = tid & 15;
    const int s = f15 >> 1;
    const int half = f15 & 1;
    const float vv[4] = {v4.x, v4.y, v4.z, v4.w};
    f16x4 hv;
    float ss = 0.0f;
    #pragma unroll
    for (int e = 0; e < 4; ++e) {
      hv[e] = (_Float16)vv[e];
      ss += vv[e] * vv[e];
    }
    ss += __shfl_xor(ss, 1);
    ss += __shfl_xor(ss, 2);
    ss += __shfl_xor(ss, 4);
    ss += __shfl_xor(ss, 8);
    if (f15 == 0) sXsq[buf][row] = ss;
    const int slot = s ^ (row & 7);           // R1-family swizzle (verified)
    *reinterpret_cast<f16x4*>(&sX[buf][row * KDIM + slot * 8 + half * 4]) = hv;
  };

  // ---- prologue ----
  float4 rx = xsrc[tid];                      // x tile 0 (oldest vmcnt)

  // centers col-half: f32 -> fp16 LDS (swizzled) + csq (norms from exact f32)
  {
    const float* cbase = centers + (size_t)nh * CPB * KDIM;
    #pragma unroll
    for (int p = 0; p < 8; ++p) {
      const int c = p * 512 + tid;            // 8-elem chunk id 0..4095
      const int row = c >> 3;                 // 0..511 (local center row)
      const int s = c & 7;
      const float4* cp = reinterpret_cast<const float4*>(cbase + (size_t)row * KDIM + s * 8);
      const float4 v0 = cp[0];
      const float4 v1 = cp[1];
      const float v[8] = {v0.x, v0.y, v0.z, v0.w, v1.x, v1.y, v1.z, v1.w};
      f16x8 hv;
      float ss = 0.0f;
      #pragma unroll
      for (int i = 0; i < 8; ++i) {
        hv[i] = (_Float16)v[i];               // RNE
        ss += v[i] * v[i];
      }
      ss += __shfl_xor(ss, 1);
      ss += __shfl_xor(ss, 2);
      ss += __shfl_xor(ss, 4);
      if (s == 0) sCsq[row] = ss;
      const int slot = s ^ (row & 7);
      *reinterpret_cast<f16x8*>(&sCen[row * KDIM + slot * 8]) = hv;
    }
  }
  convert_x(rx, 0);
  rx = xsrc[512 + tid];                       // x tile 1 in flight
  __syncthreads();                            // one-time full staging drain

  const int lane = tid & 63;
  const int wave = tid >> 6;                  // 0..7
  const int wm = wave & 1;                    // 16-row group within sub-tile
  const int wn = wave >> 1;                   // 128-col group (0..3)
  const int l = lane & 15;
  const int g = lane >> 4;                    // k-group 0..3

  // ================= 8 iterations: 32 rows x 512 cols each =================
  #pragma unroll 1
  for (int jt = 0; jt < NSUB; ++jt) {
    const int b = jt & 1;

    // stage next x sub-tile (dbuf; end-of-iter barrier protects buf b^1)
    if (jt + 1 < NSUB) convert_x(rx, b ^ 1);
    if (jt + 2 < NSUB) rx = xsrc[(jt + 2) * 512 + tid];

    // x fragments (B-operand): lane l <-> x-row, chunk g
    const int xrow = wm * 16 + l;
    f16x8 xh[2];
    #pragma unroll
    for (int ks = 0; ks < 2; ++ks) {
      const int slot = (ks * 4 + g) ^ (l & 7);
      xh[ks] = *reinterpret_cast<const f16x8*>(&sX[b][xrow * KDIM + slot * 8]);
    }
    const float xs = sXsq[b][xrow];

    const size_t rowg = (size_t)mb * RPB + jt * SUB + wm * 16 + l;
    float* orow = out + rowg * (size_t)NTOT + nh * CPB + wn * 128;

    // nf-outer: per 16-center group, 2 MFMA -> finish -> store immediately
    #pragma unroll
    for (int nf = 0; nf < 8; ++nf) {
      const int crow = wn * 128 + nf * 16 + l;
      f32x4 acc = {};
      #pragma unroll
      for (int ks = 0; ks < 2; ++ks) {
        const int slot = (ks * 4 + g) ^ (l & 7);
        const f16x8 ch = *reinterpret_cast<const f16x8*>(&sCen[crow * KDIM + slot * 8]);
        acc = __builtin_amdgcn_mfma_f32_16x16x32_f16(ch, xh[ks], acc, 0, 0, 0);
      }
      const float4 cs = *reinterpret_cast<const float4*>(&sCsq[wn * 128 + nf * 16 + g * 4]);
      float4 o;
      o.x = __expf(-GAMMA * fmaxf(xs + cs.x - 2.0f * acc[0], 0.0f));
      o.y = __expf(-GAMMA * fmaxf(xs + cs.y - 2.0f * acc[1], 0.0f));
      o.z = __expf(-GAMMA * fmaxf(xs + cs.z - 2.0f * acc[2], 0.0f));
      o.w = __expf(-GAMMA * fmaxf(xs + cs.w - 2.0f * acc[3], 0.0f));
      *reinterpret_cast<float4*>(orow + nf * 16 + g * 4) = o;
    }

    if (jt + 1 < NSUB) {
      asm volatile("s_waitcnt lgkmcnt(0)" ::: "memory");  // ds_writes visible
      __builtin_amdgcn_s_barrier();                       // raw: stores stay in flight
      __builtin_amdgcn_sched_barrier(0);                  // no hoisting across
    }
  }
}

extern "C" void kernel_launch(void* const* d_in, const int* in_sizes, int n_in,
                              void* d_out, int out_size, void* d_ws, size_t ws_size,
                              hipStream_t stream) {
  (void)in_sizes; (void)n_in; (void)d_ws; (void)ws_size; (void)out_size;
  const float* x       = (const float*)d_in[0];
  const float* centers = (const float*)d_in[1];
  float* out = (float*)d_out;
  rbf_fused_kernel<<<(MTOT / RPB) * (NTOT / CPB), 512, 0, stream>>>(x, centers, out);
}

// Round 15
// 55.748 us; speedup vs baseline: 1.0978x; 1.0978x over previous
//
#include <hip/hip_runtime.h>

#define GAMMA 0.1f

constexpr int MTOT = 65536;
constexpr int NTOT = 1024;
constexpr int KDIM = 64;
constexpr int RPB  = 256;   // rows per block; grid = 256 = exactly 1 block/CU

using f16x8 = __attribute__((ext_vector_type(8))) _Float16;  // MFMA A/B frag
using f32x4 = __attribute__((ext_vector_type(4))) float;     // MFMA C/D

// Single fused kernel, barrier-free main loop.
// Prologue: stage ALL 1024 centers as fp16 (XOR-swizzled) + csq in LDS (one
// __syncthreads). Then each wave owns 16 PRIVATE output rows: x loaded directly
// from global (issued before staging -> latency hidden), converted in-reg,
// norm via 2 shfl_xor; sweep all 64 16-col groups {2 MFMA -> finish -> float4
// store} with NO synchronization. Waves self-stagger -> stores issue
// continuously; no per-iteration barrier/imbalance losses (R13's residual).
__global__ __launch_bounds__(1024, 4)
void rbf_sweep_kernel(const float* __restrict__ x,
                      const float* __restrict__ centers,
                      float* __restrict__ out) {
  __shared__ _Float16 sCen[NTOT * KDIM];      // 128 KB, read-only after prologue
  __shared__ float    sCsq[NTOT];             // 4 KB
  // 132 KB -> 1 block/CU (16 waves)

  const int tid = threadIdx.x;
  const int mb = blockIdx.x;                  // 0..255
  const int lane = tid & 63;
  const int wave = tid >> 6;                  // 0..15
  const int l = lane & 15;
  const int g = lane >> 4;                    // k-group 0..3

  // ---- issue this wave's x row-chunk FIRST (hides under centers staging) ----
  // Lane (g,l) owns x-row (wave*16+l), k-elements ks*32+g*8 .. +8 (B-frag layout,
  // identical indexing to the R8..R13-verified sX reads).
  const float* xrp = x + ((size_t)mb * RPB + wave * 16 + l) * KDIM;
  float4 xr[4];
  #pragma unroll
  for (int ks = 0; ks < 2; ++ks) {
    xr[ks * 2]     = *reinterpret_cast<const float4*>(xrp + ks * 32 + g * 8);
    xr[ks * 2 + 1] = *reinterpret_cast<const float4*>(xrp + ks * 32 + g * 8 + 4);
  }

  // ---- stage ALL centers: f32 -> fp16 LDS (XOR-swizzled) + csq (R13 code) ----
  {
    const float4* cf = reinterpret_cast<const float4*>(centers);
    #pragma unroll
    for (int p = 0; p < 8; ++p) {
      const int c = p * 1024 + tid;           // 8-elem chunk id 0..8191
      const int row = c >> 3;                 // 0..1023
      const int s = c & 7;
      const float4 v0 = cf[c * 2];
      const float4 v1 = cf[c * 2 + 1];
      const float v[8] = {v0.x, v0.y, v0.z, v0.w, v1.x, v1.y, v1.z, v1.w};
      f16x8 hv;
      float ss = 0.0f;
      #pragma unroll
      for (int i = 0; i < 8; ++i) {
        hv[i] = (_Float16)v[i];               // RNE
        ss += v[i] * v[i];                    // norms from exact f32
      }
      ss += __shfl_xor(ss, 1);
      ss += __shfl_xor(ss, 2);
      ss += __shfl_xor(ss, 4);
      if (s == 0) sCsq[row] = ss;
      const int slot = s ^ (row & 7);         // R1-family swizzle (verified)
      *reinterpret_cast<f16x8*>(&sCen[row * KDIM + slot * 8]) = hv;
    }
  }
  __syncthreads();   // the ONLY barrier

  // ---- convert x to B-fragments + full row norm (lane-local) ----
  f16x8 xh[2];
  float ss = 0.0f;
  #pragma unroll
  for (int ks = 0; ks < 2; ++ks) {
    const float v[8] = {xr[ks*2].x,   xr[ks*2].y,   xr[ks*2].z,   xr[ks*2].w,
                        xr[ks*2+1].x, xr[ks*2+1].y, xr[ks*2+1].z, xr[ks*2+1].w};
    f16x8 h;
    #pragma unroll
    for (int e = 0; e < 8; ++e) {
      h[e] = (_Float16)v[e];
      ss += v[e] * v[e];
    }
    xh[ks] = h;
  }
  // reduce across the 4 k-groups: lane (g,l) -> full norm of row (wave*16+l)
  ss += __shfl_xor(ss, 16);
  ss += __shfl_xor(ss, 32);

  // ---- barrier-free sweep: 64 col-groups x {2 MFMA, finish, float4 store} ----
  float* orow = out + ((size_t)mb * RPB + wave * 16 + l) * (size_t)NTOT;
  #pragma unroll 8
  for (int nf = 0; nf < 64; ++nf) {
    const int crow = nf * 16 + l;             // crow&7 == l&7 (nf*16 = 0 mod 8)
    f32x4 acc = {};
    #pragma unroll
    for (int ks = 0; ks < 2; ++ks) {
      const int slot = (ks * 4 + g) ^ (l & 7);
      const f16x8 ch = *reinterpret_cast<const f16x8*>(&sCen[crow * KDIM + slot * 8]);
      acc = __builtin_amdgcn_mfma_f32_16x16x32_f16(ch, xh[ks], acc, 0, 0, 0);
    }
    // D-layout (verified R8..R13): lane (g,l) owns centers nf*16+g*4+{0..3} at
    // x-row l -> lane-local float4 store.
    const float4 cs = *reinterpret_cast<const float4*>(&sCsq[nf * 16 + g * 4]);
    float4 o;
    o.x = __expf(-GAMMA * fmaxf(ss + cs.x - 2.0f * acc[0], 0.0f));
    o.y = __expf(-GAMMA * fmaxf(ss + cs.y - 2.0f * acc[1], 0.0f));
    o.z = __expf(-GAMMA * fmaxf(ss + cs.z - 2.0f * acc[2], 0.0f));
    o.w = __expf(-GAMMA * fmaxf(ss + cs.w - 2.0f * acc[3], 0.0f));
    *reinterpret_cast<float4*>(orow + nf * 16 + g * 4) = o;
  }
}

extern "C" void kernel_launch(void* const* d_in, const int* in_sizes, int n_in,
                              void* d_out, int out_size, void* d_ws, size_t ws_size,
                              hipStream_t stream) {
  (void)in_sizes; (void)n_in; (void)d_ws; (void)ws_size; (void)out_size;
  const float* x       = (const float*)d_in[0];
  const float* centers = (const float*)d_in[1];
  float* out = (float*)d_out;
  rbf_sweep_kernel<<<MTOT / RPB, 1024, 0, stream>>>(x, centers, out);
}